// Round 1
// baseline (1100.301 us; speedup 1.0000x reference)
//
#include <hip/hip_runtime.h>
#include <cstdint>

typedef unsigned short u16;
typedef float  f32x4  __attribute__((ext_vector_type(4)));
typedef __bf16 bf16x8 __attribute__((ext_vector_type(8)));

static constexpr int Tn = 256, Bn = 64, Hn = 1024, En = 512, Vn = 32000;
static constexpr int Mn = Tn * Bn;       // 16384 rows (t-major, b-minor)
static constexpr int VT = Vn + Tn;       // 32256
static constexpr float EPSc = 1e-10f;

#define DEVFN __device__ __forceinline__

// ---------- helpers ----------
DEVFN u16 f2bf(float f) {                       // f32 -> bf16 RNE
  uint32_t u = __float_as_uint(f);
  u += 0x7fffu + ((u >> 16) & 1u);
  return (u16)(u >> 16);
}
DEVFN float bf2f(u16 h) { return __uint_as_float(((uint32_t)h) << 16); }

DEVFN float tanh_fast(float x) {
  float xc = fminf(fmaxf(x, -15.f), 15.f);
  float e2 = __expf(2.f * xc);
  return __fdividef(e2 - 1.f, e2 + 1.f);
}

DEVFN float wave_rmax(float v) {
  #pragma unroll
  for (int m = 1; m < 64; m <<= 1) v = fmaxf(v, __shfl_xor(v, m));
  return v;
}
DEVFN float wave_rsum(float v) {
  #pragma unroll
  for (int m = 1; m < 64; m <<= 1) v += __shfl_xor(v, m);
  return v;
}
DEVFN float blk_rmax(float v, float* sm) {      // 256-thread blocks
  v = wave_rmax(v);
  if ((threadIdx.x & 63) == 0) sm[threadIdx.x >> 6] = v;
  __syncthreads();
  v = fmaxf(fmaxf(sm[0], sm[1]), fmaxf(sm[2], sm[3]));
  __syncthreads();
  return v;
}
DEVFN float blk_rsum(float v, float* sm) {
  v = wave_rsum(v);
  if ((threadIdx.x & 63) == 0) sm[threadIdx.x >> 6] = v;
  __syncthreads();
  v = sm[0] + sm[1] + sm[2] + sm[3];
  __syncthreads();
  return v;
}

// ---------- conversion kernels ----------
__global__ __launch_bounds__(256) void k_conv_enc(const float* __restrict__ src,
                                                  u16* __restrict__ hi, u16* __restrict__ lo) {
  const int n8 = Mn * Hn / 8;
  for (int i = blockIdx.x * 256 + threadIdx.x; i < n8; i += gridDim.x * 256) {
    const float4* s4 = (const float4*)(src + (size_t)i * 8);
    float4 x0 = s4[0], x1 = s4[1];
    float xs[8] = {x0.x, x0.y, x0.z, x0.w, x1.x, x1.y, x1.z, x1.w};
    uint32_t hp[4], lp[4];
    #pragma unroll
    for (int j = 0; j < 4; ++j) {
      u16 h0 = f2bf(xs[2*j]),   h1 = f2bf(xs[2*j+1]);
      u16 l0 = f2bf(xs[2*j]   - bf2f(h0));
      u16 l1 = f2bf(xs[2*j+1] - bf2f(h1));
      hp[j] = (uint32_t)h0 | ((uint32_t)h1 << 16);
      lp[j] = (uint32_t)l0 | ((uint32_t)l1 << 16);
    }
    *(uint4*)(hi + (size_t)i * 8) = make_uint4(hp[0], hp[1], hp[2], hp[3]);
    *(uint4*)(lo + (size_t)i * 8) = make_uint4(lp[0], lp[1], lp[2], lp[3]);
  }
}

// attn_w second half -> bf16 (hi only); copy1_w -> hi+lo
__global__ __launch_bounds__(256) void k_conv_w(const float* __restrict__ attn_w,
                                                const float* __restrict__ copy_w,
                                                u16* __restrict__ wattn,
                                                u16* __restrict__ chi, u16* __restrict__ clo) {
  const int nA = Hn * Hn / 8;
  for (int i = blockIdx.x * 256 + threadIdx.x; i < 2 * nA; i += gridDim.x * 256) {
    if (i < nA) {
      int e = i * 8; int h = e >> 10; int k = e & 1023;
      const float4* s4 = (const float4*)(attn_w + (size_t)h * 2048 + 1024 + k);
      float4 x0 = s4[0], x1 = s4[1];
      float xs[8] = {x0.x, x0.y, x0.z, x0.w, x1.x, x1.y, x1.z, x1.w};
      uint32_t hp[4];
      #pragma unroll
      for (int j = 0; j < 4; ++j)
        hp[j] = (uint32_t)f2bf(xs[2*j]) | ((uint32_t)f2bf(xs[2*j+1]) << 16);
      *(uint4*)(wattn + (size_t)i * 8) = make_uint4(hp[0], hp[1], hp[2], hp[3]);
    } else {
      int j8 = i - nA;
      const float4* s4 = (const float4*)(copy_w + (size_t)j8 * 8);
      float4 x0 = s4[0], x1 = s4[1];
      float xs[8] = {x0.x, x0.y, x0.z, x0.w, x1.x, x1.y, x1.z, x1.w};
      uint32_t hp[4], lp[4];
      #pragma unroll
      for (int j = 0; j < 4; ++j) {
        u16 h0 = f2bf(xs[2*j]),   h1 = f2bf(xs[2*j+1]);
        u16 l0 = f2bf(xs[2*j]   - bf2f(h0));
        u16 l1 = f2bf(xs[2*j+1] - bf2f(h1));
        hp[j] = (uint32_t)h0 | ((uint32_t)h1 << 16);
        lp[j] = (uint32_t)l0 | ((uint32_t)l1 << 16);
      }
      *(uint4*)(chi + (size_t)j8 * 8) = make_uint4(hp[0], hp[1], hp[2], hp[3]);
      *(uint4*)(clo + (size_t)j8 * 8) = make_uint4(lp[0], lp[1], lp[2], lp[3]);
    }
  }
}

// ---------- init / bias / zero / gather kernel ----------
__global__ __launch_bounds__(256) void k_init(const float* __restrict__ attn_b,
                                              const float* __restrict__ last_h,
                                              const int* __restrict__ z,
                                              const float* __restrict__ emb_t,
                                              const float* __restrict__ ectrl_b,
                                              const float* __restrict__ fh_b,
                                              float* __restrict__ hid_proj,
                                              float* __restrict__ ffnn_in,
                                              float* __restrict__ ez_emb,
                                              float* __restrict__ att,
                                              float* __restrict__ sbuf,
                                              float* __restrict__ lh_out,
                                              float* __restrict__ proba) {
  const int total = 65536 + 65536 + 32768 + 32768 + 32768 + 65536 + Bn * VT;
  for (int i = blockIdx.x * 256 + threadIdx.x; i < total; i += gridDim.x * 256) {
    int x = i;
    if (x < 65536) { hid_proj[x] = attn_b[x & 1023]; continue; }
    x -= 65536;
    if (x < 65536) { int b = x >> 10, h = x & 1023; ffnn_in[b*2560 + 1536 + h] = last_h[x]; continue; }
    x -= 65536;
    if (x < 32768) { int b = x >> 9, e = x & 511;
                     ffnn_in[b*2560 + e] = ectrl_b[e] + emb_t[(size_t)z[b]*512 + e]; continue; }
    x -= 32768;
    if (x < 32768) { int b = x >> 9, e = x & 511; ez_emb[x] = emb_t[(size_t)z[b]*512 + e]; continue; }
    x -= 32768;
    if (x < 32768) { if (x < 16384) att[x] = 0.f; else sbuf[x - 16384] = 0.f; continue; }
    x -= 32768;
    if (x < 65536) { lh_out[x] = fh_b[x & 1023]; continue; }
    x -= 65536;
    proba[x] = 0.f;
  }
}

// ---------- reduced MFMA GEMM: out[r] += sum_h tanh(A[r,:]@W[h,:] + extra) * vec ----------
// A: (16384 x 1024) bf16 row-major (hi [+lo]); W: (1024 x 1024) bf16 row-major.
// grid = (256 row-tiles of 64, 8 col-splits of 128). 4 waves as 2x2. BK=64.
// LDS chunk-XOR swizzle ch^(row&7) on both ds_write and ds_read (16B units).
template<bool SPLIT, bool EB, bool VB>
__global__ __launch_bounds__(256) void k_redgemm(const u16* __restrict__ Ahi, const u16* __restrict__ Alo,
                                                 const u16* __restrict__ Whi, const u16* __restrict__ Wlo,
                                                 const float* __restrict__ extra,
                                                 const float* __restrict__ vec,
                                                 float* __restrict__ out) {
  constexpr int AB = 64 * 128;     // bytes per A tile buffer
  constexpr int WB = 128 * 128;
  __shared__ uint4 ldsbuf[(SPLIT ? (2*AB + 2*WB) : (AB + WB)) / 16];
  char* ldsA  = (char*)ldsbuf;
  char* ldsAl = ldsA + AB;
  char* ldsW  = ldsA + (SPLIT ? 2*AB : AB);
  char* ldsWl = ldsW + WB;

  const int tid  = threadIdx.x;
  const int lane = tid & 63;
  const int wid  = tid >> 6;
  const int wm = wid >> 1, wn = wid & 1;
  const int lr = lane >> 4, lc = lane & 15;
  const int row0 = blockIdx.x * 64;
  const int h0   = blockIdx.y * 128;

  f32x4 z4 = {0.f, 0.f, 0.f, 0.f};
  f32x4 acc[2][4];
  #pragma unroll
  for (int i = 0; i < 2; ++i)
    #pragma unroll
    for (int j = 0; j < 4; ++j) acc[i][j] = z4;

  for (int ks = 0; ks < 16; ++ks) {
    const int k0 = ks * 64;
    #pragma unroll
    for (int i = 0; i < 2; ++i) {               // A: 64 rows x 128B
      int u = tid + i * 256;
      int row = u >> 3, ch = u & 7;
      int sw = ch ^ (row & 7);
      size_t go = (size_t)(row0 + row) * 1024 + k0 + ch * 8;
      *(uint4*)(ldsA + row * 128 + sw * 16) = *(const uint4*)(Ahi + go);
      if (SPLIT) *(uint4*)(ldsAl + row * 128 + sw * 16) = *(const uint4*)(Alo + go);
    }
    #pragma unroll
    for (int i = 0; i < 4; ++i) {               // W: 128 rows x 128B
      int u = tid + i * 256;
      int row = u >> 3, ch = u & 7;
      int sw = ch ^ (row & 7);
      size_t go = (size_t)(h0 + row) * 1024 + k0 + ch * 8;
      *(uint4*)(ldsW + row * 128 + sw * 16) = *(const uint4*)(Whi + go);
      if (SPLIT) *(uint4*)(ldsWl + row * 128 + sw * 16) = *(const uint4*)(Wlo + go);
    }
    __syncthreads();
    #pragma unroll
    for (int kk = 0; kk < 2; ++kk) {
      const int cg = kk * 4 + lr;
      bf16x8 ah[2], al[2], bh[4], bl[4];
      #pragma unroll
      for (int mf = 0; mf < 2; ++mf) {
        int ar = wm * 32 + mf * 16 + lc;
        int off = ar * 128 + ((cg ^ (ar & 7)) << 4);
        ah[mf] = *(const bf16x8*)(ldsA + off);
        if (SPLIT) al[mf] = *(const bf16x8*)(ldsAl + off);
      }
      #pragma unroll
      for (int nf = 0; nf < 4; ++nf) {
        int wr = wn * 64 + nf * 16 + lc;
        int off = wr * 128 + ((cg ^ (wr & 7)) << 4);
        bh[nf] = *(const bf16x8*)(ldsW + off);
        if (SPLIT) bl[nf] = *(const bf16x8*)(ldsWl + off);
      }
      #pragma unroll
      for (int mf = 0; mf < 2; ++mf)
        #pragma unroll
        for (int nf = 0; nf < 4; ++nf) {
          acc[mf][nf] = __builtin_amdgcn_mfma_f32_16x16x32_bf16(ah[mf], bh[nf], acc[mf][nf], 0, 0, 0);
          if (SPLIT) {
            acc[mf][nf] = __builtin_amdgcn_mfma_f32_16x16x32_bf16(al[mf], bh[nf], acc[mf][nf], 0, 0, 0);
            acc[mf][nf] = __builtin_amdgcn_mfma_f32_16x16x32_bf16(ah[mf], bl[nf], acc[mf][nf], 0, 0, 0);
          }
        }
    }
    __syncthreads();
  }

  // epilogue: tanh(+extra), weight by vec, reduce over the 128 h's of this block
  // row0 % 64 == 0  =>  b == local row index (rows are t*64+b)
  #pragma unroll
  for (int mf = 0; mf < 2; ++mf) {
    #pragma unroll
    for (int r = 0; r < 4; ++r) {
      int ml = wm * 32 + mf * 16 + lr * 4 + r;          // == b
      float sum = 0.f;
      #pragma unroll
      for (int nf = 0; nf < 4; ++nf) {
        int h = h0 + wn * 64 + nf * 16 + lc;
        float x = acc[mf][nf][r] + (EB ? extra[ml * 1024 + h] : extra[h]);
        sum += tanh_fast(x) * (VB ? vec[ml * 1024 + h] : vec[h]);
      }
      #pragma unroll
      for (int mM = 1; mM < 16; mM <<= 1) sum += __shfl_xor(sum, mM);
      if (lc == 0) atomicAdd(&out[row0 + ml], sum);
    }
  }
}

// ---------- fp32 register-tiled GEMM: out[b,n] (+)= A[b,:]@W[n,:] (+bias). 64 rows fixed. ----------
// grid = (N/128, KSPLIT). 256 thr as 8(b-groups) x 32(n-groups); thread tile 8b x 4n. BK=32.
template<bool ATOMIC, bool BIAS>
__global__ __launch_bounds__(256) void k_sgemm(const float* __restrict__ A, int lda,
                                               const float* __restrict__ W, int ldw,
                                               float* __restrict__ out, int ldo,
                                               const float* __restrict__ bias, int kchunk) {
  __shared__ float Asm[32][68];     // [kk][b]  (+pad vs bank conflicts)
  __shared__ float Wsm[32][132];    // [kk][n]
  const int tid = threadIdx.x;
  const int bg = tid >> 5, ng = tid & 31;
  const int n0 = blockIdx.x * 128;
  const int kbeg = blockIdx.y * kchunk;

  float acc[8][4];
  #pragma unroll
  for (int i = 0; i < 8; ++i)
    #pragma unroll
    for (int j = 0; j < 4; ++j) acc[i][j] = 0.f;

  for (int k0 = kbeg; k0 < kbeg + kchunk; k0 += 32) {
    #pragma unroll
    for (int i = 0; i < 8; ++i) {
      int u = tid + i * 256; int b = u >> 5, kk = u & 31;
      Asm[kk][b] = A[(size_t)b * lda + k0 + kk];
    }
    #pragma unroll
    for (int i = 0; i < 16; ++i) {
      int u = tid + i * 256; int n = u >> 5, kk = u & 31;
      Wsm[kk][n] = W[(size_t)(n0 + n) * ldw + k0 + kk];
    }
    __syncthreads();
    #pragma unroll 4
    for (int kk = 0; kk < 32; ++kk) {
      float4 a0 = *(const float4*)&Asm[kk][bg * 8];
      float4 a1 = *(const float4*)&Asm[kk][bg * 8 + 4];
      float4 w  = *(const float4*)&Wsm[kk][ng * 4];
      float av[8] = {a0.x, a0.y, a0.z, a0.w, a1.x, a1.y, a1.z, a1.w};
      float wv[4] = {w.x, w.y, w.z, w.w};
      #pragma unroll
      for (int ii = 0; ii < 8; ++ii)
        #pragma unroll
        for (int jj = 0; jj < 4; ++jj) acc[ii][jj] = fmaf(av[ii], wv[jj], acc[ii][jj]);
    }
    __syncthreads();
  }
  #pragma unroll
  for (int ii = 0; ii < 8; ++ii) {
    int b = bg * 8 + ii;
    #pragma unroll
    for (int jj = 0; jj < 4; ++jj) {
      int n = n0 + ng * 4 + jj;
      float v = acc[ii][jj];
      if (BIAS) v += bias[n];
      if (ATOMIC) atomicAdd(&out[(size_t)b * ldo + n], v);
      else out[(size_t)b * ldo + n] = v;
    }
  }
}

// ---------- attention softmax over t (per b) ----------
__global__ __launch_bounds__(256) void k_rowsoftmax(const float* __restrict__ att, float* __restrict__ alpha) {
  __shared__ float sm[4];
  int b = blockIdx.x, t = threadIdx.x;
  float v = att[t * 64 + b];
  float mx = blk_rmax(v, sm);
  float e = __expf(v - mx);
  float s = blk_rsum(e, sm);
  alpha[b * 256 + t] = e / s;
}

// ---------- context[b,h] = sum_t alpha * enc[t,b,h], written into ffnn_in[:,512:1536] ----------
__global__ __launch_bounds__(256) void k_context(const float* __restrict__ enc, const float* __restrict__ alpha,
                                                 float* __restrict__ ffnn_in) {
  __shared__ float al[256];
  int b = blockIdx.y;
  int h = blockIdx.x * 256 + threadIdx.x;
  al[threadIdx.x] = alpha[b * 256 + threadIdx.x];
  __syncthreads();
  float acc = 0.f;
  #pragma unroll 4
  for (int t = 0; t < 256; ++t)
    acc = fmaf(al[t], enc[((size_t)t * 64 + b) * 1024 + h], acc);
  ffnn_in[b * 2560 + 512 + h] = acc;
}

// ---------- copy mechanism: per-b softmax stats over s, scatter (1-EPS)e into proba(agg) ----------
__global__ __launch_bounds__(256) void k_copyprep(const float* __restrict__ sbuf, const int* __restrict__ u_inp,
                                                  float* __restrict__ proba, float* __restrict__ smax_a,
                                                  float* __restrict__ total_a, float* __restrict__ sagg_a) {
  __shared__ float sm[4];
  int b = blockIdx.x, t = threadIdx.x;
  float sv = sbuf[t * 64 + b];
  float mx = blk_rmax(sv, sm);
  float e = __expf(sv - mx);
  float tot = blk_rsum(e, sm);
  int w = u_inp[t * 64 + b];
  float sni = blk_rsum((w != 0) ? e : 0.f, sm);
  if (w != 0) {
    int col = (w == 2) ? (Vn + t) : w;     // UNK -> V+t ; IGN (0) dropped
    atomicAdd(&proba[(size_t)b * VT + col], (1.f - EPSc) * e);
  }
  if (t == 0) { smax_a[b] = mx; total_a[b] = tot; sagg_a[b] = (1.f - EPSc) * sni; }
}

// ---------- joint softmax stats over [gen | u_copy] (u_copy folded analytically) ----------
__global__ __launch_bounds__(256) void k_finalA(const float* __restrict__ gen, const float* __restrict__ proba,
                                                const float* __restrict__ smax_a, const float* __restrict__ total_a,
                                                const float* __restrict__ sagg_a,
                                                float* __restrict__ m_a, float* __restrict__ fac_a,
                                                float* __restrict__ invD_a) {
  __shared__ float sm[4];
  int b = blockIdx.x, t = threadIdx.x;
  float gm = -3.4e38f;
  for (int j = t; j < Vn; j += 256) gm = fmaxf(gm, gen[(size_t)b * Vn + j]);
  gm = blk_rmax(gm, sm);
  float am = 0.f;
  for (int j = t; j < VT; j += 256) am = fmaxf(am, proba[(size_t)b * VT + j]);
  am = blk_rmax(am, sm);
  float smax = smax_a[b], tot = total_a[b];
  float m = fmaxf(gm, smax + logf(EPSc * tot + am));
  float se = 0.f;
  for (int j = t; j < Vn; j += 256) se += __expf(gen[(size_t)b * Vn + j] - m);
  se = blk_rsum(se, sm);
  if (t == 0) {
    float fac = __expf(smax - m);
    float D = se + fac * (EPSc * tot * (float)VT + sagg_a[b]);
    m_a[b] = m; fac_a[b] = fac; invD_a[b] = 1.f / D;
  }
}

// ---------- final: proba[b,j] = (exp(gen-m) [j<V] + (EPS*total+agg)*fac) / D, in-place ----------
__global__ __launch_bounds__(256) void k_finalB(const float* __restrict__ gen,
                                                const float* __restrict__ m_a, const float* __restrict__ fac_a,
                                                const float* __restrict__ invD_a, const float* __restrict__ total_a,
                                                float* __restrict__ proba) {
  int b = blockIdx.y;
  int j = blockIdx.x * 256 + threadIdx.x;     // 126*256 == 32256 exactly
  size_t idx = (size_t)b * VT + j;
  float agg = proba[idx];
  float p = (EPSc * total_a[b] + agg) * fac_a[b];
  if (j < Vn) p += __expf(gen[(size_t)b * Vn + j] - m_a[b]);
  proba[idx] = p * invD_a[b];
}

// ---------- launch ----------
extern "C" void kernel_launch(void* const* d_in, const int* in_sizes, int n_in,
                              void* d_out, int out_size, void* d_ws, size_t ws_size,
                              hipStream_t stream) {
  (void)in_sizes; (void)n_in; (void)out_size; (void)ws_size;
  const float* u_enc   = (const float*)d_in[0];
  const float* last_h  = (const float*)d_in[1];
  const int*   z_tm1   = (const int*)d_in[2];
  const int*   u_inp   = (const int*)d_in[3];
  const float* emb_t   = (const float*)d_in[4];
  const float* ectrl_w = (const float*)d_in[5];
  const float* ectrl_b = (const float*)d_in[6];
  const float* attn_w  = (const float*)d_in[7];
  const float* attn_b  = (const float*)d_in[8];
  const float* attn_v  = (const float*)d_in[9];
  const float* fh_w    = (const float*)d_in[10];
  const float* fh_b    = (const float*)d_in[11];
  const float* fo_w    = (const float*)d_in[12];
  const float* fo_b    = (const float*)d_in[13];
  const float* c1_w    = (const float*)d_in[14];
  const float* c1_b    = (const float*)d_in[15];

  float* lh_out = (float*)d_out;               // (1,B,H) = 64x1024
  float* proba  = (float*)d_out + 65536;       // (B, V+T) = 64x32256 (also agg buffer)

  char* ws = (char*)d_ws;                      // ~82.9 MB used
  u16*  enc_hi   = (u16*)(ws + 0);             // 33.5 MB
  u16*  enc_lo   = (u16*)(ws + 33554432);      // 33.5 MB
  u16*  w_attn   = (u16*)(ws + 67108864);      // 2 MB
  u16*  w_chi    = (u16*)(ws + 69206016);      // 2 MB
  u16*  w_clo    = (u16*)(ws + 71303168);      // 2 MB
  float* hid_proj= (float*)(ws + 73400320);    // 64x1024
  float* ffnn_in = (float*)(ws + 73662464);    // 64x2560
  float* ez_emb  = (float*)(ws + 74317824);    // 64x512
  float* att     = (float*)(ws + 74448896);    // 16384
  float* sbuf    = (float*)(ws + 74514432);    // 16384
  float* alpha   = (float*)(ws + 74579968);    // 64x256
  float* gen     = (float*)(ws + 74645504);    // 64x32000
  float* smax_a  = (float*)(ws + 82837504);
  float* total_a = smax_a + 64;
  float* sagg_a  = smax_a + 128;
  float* m_a     = smax_a + 192;
  float* fac_a   = smax_a + 256;
  float* invD_a  = smax_a + 320;

  k_conv_enc<<<2048, 256, 0, stream>>>(u_enc, enc_hi, enc_lo);
  k_conv_w<<<1024, 256, 0, stream>>>(attn_w, c1_w, w_attn, w_chi, w_clo);
  k_init<<<4096, 256, 0, stream>>>(attn_b, last_h, z_tm1, emb_t, ectrl_b, fh_b,
                                   hid_proj, ffnn_in, ez_emb, att, sbuf, lh_out, proba);
  // hid_proj = hid @ attn_w[:, :H]^T  (+attn_b via init)
  k_sgemm<true,  false><<<dim3(8, 8),   256, 0, stream>>>(last_h, 1024, attn_w, 2048, hid_proj, 1024, nullptr, 128);
  // att[t*64+b] = sum_h tanh(enc@W2^T + hid_proj) * attn_v
  k_redgemm<false, true, false><<<dim3(256, 8), 256, 0, stream>>>(enc_hi, nullptr, w_attn, nullptr,
                                                                  hid_proj, attn_v, att);
  k_rowsoftmax<<<64, 256, 0, stream>>>(att, alpha);
  k_context<<<dim3(4, 64), 256, 0, stream>>>(u_enc, alpha, ffnn_in);
  // ez part of ffnn_in (+bias+residual via init)
  k_sgemm<true,  false><<<dim3(4, 4),   256, 0, stream>>>(ez_emb, 512, ectrl_w, 512, ffnn_in, 2560, nullptr, 128);
  // lh (+bias via init), written straight into d_out
  k_sgemm<true,  false><<<dim3(8, 8),   256, 0, stream>>>(ffnn_in, 2560, fh_w, 2560, lh_out, 1024, nullptr, 320);
  // gen_score
  k_sgemm<false, true ><<<dim3(250, 1), 256, 0, stream>>>(lh_out, 1024, fo_w, 1024, gen, 32000, fo_b, 1024);
  // s[t*64+b] = sum_h tanh(enc@copy1^T + copy1_b) * lh   (split bf16 for precision)
  k_redgemm<true, false, true><<<dim3(256, 8), 256, 0, stream>>>(enc_hi, enc_lo, w_chi, w_clo,
                                                                 c1_b, lh_out, sbuf);
  k_copyprep<<<64, 256, 0, stream>>>(sbuf, u_inp, proba, smax_a, total_a, sagg_a);
  k_finalA<<<64, 256, 0, stream>>>(gen, proba, smax_a, total_a, sagg_a, m_a, fac_a, invD_a);
  k_finalB<<<dim3(126, 64), 256, 0, stream>>>(gen, m_a, fac_a, invD_a, total_a, proba);
}